// Round 2
// 779.986 us; speedup vs baseline: 1.0089x; 1.0089x over previous
//
#include <hip/hip_runtime.h>
#include <hip/hip_bf16.h>

// LSTM2: B=1024, T=1024, H=64. R18: R17 with the DPP head-reduce direction
// bug fixed. R17's row_shr:1/2/4/8 chain accumulates toward HIGHER lanes
// (lane i receives lane i-N, OOB->0), so the 16-lane sum lands in uo==15,
// not uo==0. R17 stored from uo==0 -> head partials held 1/16 of the sum
// (absmax 0.137, recurrence unaffected). Fix: store from uo==15.
// R17 changes retained:
//  (a) exec-masked h-frag reads (m<NBat): cut LDS pipe ~4x on h reads.
//  (b) #pragma unroll 2: parity (t&1) folds per copy.
//  (c) sigmoid/tanh input scales folded into W/bias at load (per-gate rows:
//      -log2e for i,f,o; -2log2e for g).
//  (d) head reduce via DPP row_shr adds (sum at uo==15).
//  (e) s_setprio(1) around MFMA clusters.
// Structure: 256 blocks (4 batches) x 8 waves, P-waves 0-3 run L1 at t,
// Q-waves 4-7 run L2 one step behind; ONE block barrier per interval.
// Parity audit: h1 W:t&1 R:(t-1)&1; h2 W:(t-1)&1 R:t&1; headl W:(t-1)&1
// R:t&1 -- write!=read parity, reuse separated by a barrier.
// Layouts (m89/m91/m120): A[m=lane&15][k=(lane>>4)*8+j],
// B[k=(lane>>4)*8+j][n=lane&15], C/D: row=(lane>>4)*4+reg, col=lane&15.

typedef _Float16 f16x8 __attribute__((ext_vector_type(8)));
typedef float    f32x4 __attribute__((ext_vector_type(4)));

namespace {
constexpr int Bb = 1024;
constexpr int Tt = 1024;
constexpr int NBat = 4;    // batches per block
constexpr int HSTR = 72;   // f16 stride per batch row of h
constexpr int XSTR = 1025; // f32 stride per batch row of x

__device__ __forceinline__ int srow(int row) {      // XOR bank swizzle (R11)
    return row ^ ((row >> 3) & 7);
}
// Pre-scaled activations: gate rows of W/b are folded with -log2(e) (i,f,o)
// and -2*log2(e) (g) at load time, so no input multiply here.
__device__ __forceinline__ float sigm_pre(float a) {   // a = -1.4427*x
    return __builtin_amdgcn_rcpf(1.0f + __builtin_amdgcn_exp2f(a));
}
__device__ __forceinline__ float tanh_pre(float a) {   // a = -2.8854*x
    return fmaf(2.0f, __builtin_amdgcn_rcpf(1.0f + __builtin_amdgcn_exp2f(a)), -1.0f);
}
__device__ __forceinline__ float tanh_f(float x) {     // unscaled input (c-path)
    float e = __builtin_amdgcn_exp2f(-2.8853900817779268f * x);
    return fmaf(2.0f, __builtin_amdgcn_rcpf(1.0f + e), -1.0f);
}
// DPP partial-sum step: lane i += lane (i-N) within its 16-lane DPP row
// (OOB lanes contribute 0 via bound_ctrl). Sum accumulates toward lane 15.
template <int CTRL>
__device__ __forceinline__ float dpp_sum_step(float p) {
    int v = __builtin_amdgcn_update_dpp(0, __float_as_int(p), CTRL, 0xf, 0xf, true);
    return p + __int_as_float(v);
}
// Dtype sniff (proven R2-R16).
__device__ __forceinline__ bool detect_f32(const void* w) {
    const unsigned short* p = (const unsigned short*)w;
    int sane = 0;
    for (int i = 0; i < 64; ++i) {
        int e = (p[2 * i] >> 7) & 0xFF;
        if (e >= 107 && e <= 129) ++sane;
    }
    return sane < 32;
}
__device__ __forceinline__ float ld(const void* p, int i, bool f32) {
    return f32 ? ((const float*)p)[i]
               : __bfloat162float(((const __hip_bfloat16*)p)[i]);
}
__device__ __forceinline__ void st(void* p, int i, float v, bool f32) {
    if (f32) ((float*)p)[i] = v;
    else     ((__hip_bfloat16*)p)[i] = __float2bfloat16(v);
}
} // namespace

__global__ __launch_bounds__(512, 1) void lstm2_kernel(
    const void* __restrict__ x,      // [B, T]
    const void* __restrict__ w_ih1,  // [256, 1]
    const void* __restrict__ w_hh1,  // [256, 64]
    const void* __restrict__ b_ih1,  // [256]
    const void* __restrict__ b_hh1,  // [256]
    const void* __restrict__ w_ih2,  // [256, 64]
    const void* __restrict__ w_hh2,  // [256, 64]
    const void* __restrict__ b_ih2,  // [256]
    const void* __restrict__ b_hh2,  // [256]
    const void* __restrict__ w_lin,  // [1, 64]
    const void* __restrict__ b_lin,  // [1]
    void* __restrict__ out)          // [B, T]
{
    const int tid  = threadIdx.x;
    const int lane = tid & 63;
    const int w    = tid >> 6;       // wave 0..7
    const int gw   = w & 3;          // group-local wave -> unit group 16gw..
    const bool isP = w < 4;          // P: L1 fast loop; Q: L2 pipeline
    const int m    = lane & 15;      // MFMA col (batch; valid m<NBat)
    const int quad = lane >> 4;
    const int bb   = blockIdx.x * NBat;

    const bool f32 = detect_f32(w_hh1);

    __shared__ float                  xs[NBat * XSTR];
    __shared__ __align__(16) _Float16 h1buf[2][16 * HSTR];  // parity-buffered
    __shared__ __align__(16) _Float16 h2buf[2][16 * HSTR];
    __shared__ __align__(16) float    scr1[4][64 * 4];      // P-wave scratch
    __shared__ __align__(16) float    scr2[4][64 * 4];      // Q-wave scratch
    __shared__ float                  headl[2][16];         // [parity][gw*4+b]
    __shared__ float                  outbuf[NBat * Tt];    // staged outputs

    // ---- stage x + zero h buffers (rows >= NBat stay 0 forever) ----
    for (int i = tid; i < NBat * 1024; i += 512)
        xs[(i >> 10) * XSTR + (i & 1023)] = ld(x, (bb + (i >> 10)) * Tt + (i & 1023), f32);
    for (int i = tid; i < 16 * HSTR; i += 512) {
        h1buf[0][i] = (_Float16)0; h1buf[1][i] = (_Float16)0;
        h2buf[0][i] = (_Float16)0; h2buf[1][i] = (_Float16)0;
    }

    // ---- A-fragments, gate-interleaved rows (R13), activation-scale folded ----
    // tile row (lane&15) = 4*u_loc + g -> mem row 64*g + 16*gw + 4q + u_loc
    const int arow = lane & 15;
    const int g_ld = arow & 3;
    const int u_ld = arow >> 2;
    const float scA = (g_ld == 2) ? -2.8853900817779268f : -1.4426950408889634f;
    f16x8 wfA[4][2], wfB[4][2];   // P: wfA=W1 (wfB zero); Q: wfA=W2, wfB=W3
    {
        const void* MA = isP ? w_hh1 : w_ih2;
#pragma unroll
        for (int q = 0; q < 4; ++q) {
            const int row = 64 * g_ld + 16 * gw + 4 * q + u_ld;
#pragma unroll
            for (int s = 0; s < 2; ++s) {
                const int base = row * 64 + 32 * s + quad * 8;
                if (f32) {
                    const float* A = (const float*)MA;
                    const float* B = (const float*)w_hh2;
#pragma unroll
                    for (int j = 0; j < 8; ++j) {
                        wfA[q][s][j] = (_Float16)(scA * A[base + j]);
                        wfB[q][s][j] = isP ? (_Float16)0.0f
                                           : (_Float16)(scA * B[base + j]);
                    }
                } else {
                    const __hip_bfloat16* A = (const __hip_bfloat16*)MA;
                    const __hip_bfloat16* B = (const __hip_bfloat16*)w_hh2;
#pragma unroll
                    for (int j = 0; j < 8; ++j) {
                        wfA[q][s][j] = (_Float16)(scA * __bfloat162float(A[base + j]));
                        wfB[q][s][j] = isP ? (_Float16)0.0f
                                           : (_Float16)(scA * __bfloat162float(B[base + j]));
                    }
                }
            }
        }
    }
    // bias / wx per (tile q, gate r): D row r of tile q = gate r, unit 16gw+4q+quad
    f32x4 bv[4], wxv[4];
#pragma unroll
    for (int q = 0; q < 4; ++q)
#pragma unroll
        for (int r = 0; r < 4; ++r) {
            const int row = 64 * r + 16 * gw + 4 * q + quad;
            const float sg = (r == 2) ? -2.8853900817779268f : -1.4426950408889634f;
            bv[q][r] = sg * (isP ? (ld(b_ih1, row, f32) + ld(b_hh1, row, f32))
                                 : (ld(b_ih2, row, f32) + ld(b_hh2, row, f32)));
            wxv[q][r] = isP ? sg * ld(w_ih1, row, f32) : 0.0f;
        }
    // cell mapping: lane -> (batch cb, unit 16gw+uo)
    const int cb = lane >> 4;
    const int uo = lane & 15;
    const int cidx = srow(lane) * 4;
    // scr write addresses are loop-invariant per lane (valid for m<NBat)
    int swadr[4];
#pragma unroll
    for (int q = 0; q < 4; ++q) swadr[q] = srow(m * 16 + q * 4 + quad) * 4;
    const float wl_u = ld(w_lin, 16 * gw + uo, f32);
    const float blin = ld(b_lin, 0, f32);
    float cst = 0.0f;                 // c1 (P) or c2 (Q)
    // persistent masked h-fragments: lanes m>=NBat keep these zeros forever
    f16x8 pa0{}, pa1{}, pb0{}, pb1{};
    __syncthreads();   // xs + zeroed h bufs visible

#pragma unroll 2
    for (int t = 0; t <= Tt; ++t) {
        if (isP) {
            if (t < Tt) {
                // ---- a1(t) = W1.h1(t-1) + x_t*wx + b1 (pre-scaled) ----
                f32x4 acc[4];
                const float xt = xs[(m & (NBat - 1)) * XSTR + t];
#pragma unroll
                for (int q = 0; q < 4; ++q)
#pragma unroll
                    for (int r = 0; r < 4; ++r)
                        acc[q][r] = fmaf(xt, wxv[q][r], bv[q][r]);
                if (t > 0) {
                    const _Float16* hp = h1buf[(t - 1) & 1] + m * HSTR;
                    if (m < NBat) {       // masked read: only valid batches
                        pa0 = *(const f16x8*)(hp + quad * 8);
                        pa1 = *(const f16x8*)(hp + 32 + quad * 8);
                    }
                    __builtin_amdgcn_s_setprio(1);
#pragma unroll
                    for (int q = 0; q < 4; ++q) {
                        acc[q] = __builtin_amdgcn_mfma_f32_16x16x32_f16(wfA[q][0], pa0, acc[q], 0, 0, 0);
                        acc[q] = __builtin_amdgcn_mfma_f32_16x16x32_f16(wfA[q][1], pa1, acc[q], 0, 0, 0);
                    }
                    __builtin_amdgcn_s_setprio(0);
                }
                if (m < NBat)
#pragma unroll
                    for (int q = 0; q < 4; ++q)
                        *(f32x4*)&scr1[gw][swadr[q]] = acc[q];
                // ---- cell1(t): 1 eval/lane ----
                const f32x4 g = *(const f32x4*)&scr1[gw][cidx];   // i,f,g,o
                float ig = sigm_pre(g[0]), fg = sigm_pre(g[1]);
                float gg = tanh_pre(g[2]), og = sigm_pre(g[3]);
                cst = fmaf(fg, cst, ig * gg);
                h1buf[t & 1][cb * HSTR + 16 * gw + uo] = (_Float16)(og * tanh_f(cst));
            }
        } else {
            if (t > 0) {
                // ---- finalize out(t-2) -> LDS outbuf (no global store) ----
                if (t > 1 && w == 4 && lane < NBat) {
                    float s = blin;
#pragma unroll
                    for (int k = 0; k < 4; ++k) s += headl[t & 1][k * 4 + lane];
                    outbuf[lane * Tt + (t - 2)] = s;
                }
                // ---- a2(t-1) = W2.h1(t-1) + W3.h2(t-2) + b2 (pre-scaled) ----
                const _Float16* h1p = h1buf[(t - 1) & 1] + m * HSTR;
                const _Float16* h2p = h2buf[t & 1] + m * HSTR;
                if (m < NBat) {           // masked reads: only valid batches
                    pa0 = *(const f16x8*)(h1p + quad * 8);
                    pa1 = *(const f16x8*)(h1p + 32 + quad * 8);
                    pb0 = *(const f16x8*)(h2p + quad * 8);
                    pb1 = *(const f16x8*)(h2p + 32 + quad * 8);
                }
                f32x4 acc[4];
                __builtin_amdgcn_s_setprio(1);
#pragma unroll
                for (int q = 0; q < 4; ++q) {   // two independent 2-deep chains
                    f32x4 p2 = __builtin_amdgcn_mfma_f32_16x16x32_f16(wfA[q][0], pa0, bv[q], 0, 0, 0);
                    p2 = __builtin_amdgcn_mfma_f32_16x16x32_f16(wfA[q][1], pa1, p2, 0, 0, 0);
                    f32x4 p3 = __builtin_amdgcn_mfma_f32_16x16x32_f16(wfB[q][0], pb0, f32x4{0,0,0,0}, 0, 0, 0);
                    p3 = __builtin_amdgcn_mfma_f32_16x16x32_f16(wfB[q][1], pb1, p3, 0, 0, 0);
                    acc[q] = p2 + p3;
                }
                __builtin_amdgcn_s_setprio(0);
                if (m < NBat)
#pragma unroll
                    for (int q = 0; q < 4; ++q)
                        *(f32x4*)&scr2[gw][swadr[q]] = acc[q];
                // ---- cell2(t-1): 1 eval/lane + head partial ----
                const f32x4 g = *(const f32x4*)&scr2[gw][cidx];
                float ig = sigm_pre(g[0]), fg = sigm_pre(g[1]);
                float gg = tanh_pre(g[2]), og = sigm_pre(g[3]);
                cst = fmaf(fg, cst, ig * gg);
                float h = og * tanh_f(cst);
                h2buf[(t - 1) & 1][cb * HSTR + 16 * gw + uo] = (_Float16)h;
                float p = h * wl_u;               // reduce over uo (same cb)
                p = dpp_sum_step<0x111>(p);       // row_shr:1
                p = dpp_sum_step<0x112>(p);       // row_shr:2
                p = dpp_sum_step<0x114>(p);       // row_shr:4
                p = dpp_sum_step<0x118>(p);       // row_shr:8
                if (uo == 15) headl[(t - 1) & 1][gw * 4 + cb] = p;  // sum at lane 15
            }
        }
        __syncthreads();   // interval barrier: h1(t), h2(t-1), headl(t-1) visible
    }

    // ---- final: out(Tt-1) partials -> outbuf ----
    if (w == 4 && lane < NBat) {
        float s = blin;
#pragma unroll
        for (int k = 0; k < 4; ++k) s += headl[(Tt - 1) & 1][k * 4 + lane];
        outbuf[lane * Tt + (Tt - 1)] = s;
    }
    __syncthreads();
    // ---- cooperative coalesced flush: LDS outbuf -> global out ----
    for (int i = tid; i < NBat * Tt; i += 512)
        st(out, (bb + (i >> 10)) * Tt + (i & 1023), outbuf[i], f32);
}

extern "C" void kernel_launch(void* const* d_in, const int* in_sizes, int n_in,
                              void* d_out, int out_size, void* d_ws, size_t ws_size,
                              hipStream_t stream)
{
    (void)in_sizes; (void)n_in; (void)out_size; (void)d_ws; (void)ws_size;
    lstm2_kernel<<<dim3(Bb / NBat), dim3(512), 0, stream>>>(
        d_in[0], d_in[1], d_in[2], d_in[3], d_in[4], d_in[5],
        d_in[6], d_in[7], d_in[8], d_in[9], d_in[10], d_out);
}

// Round 4
// 757.844 us; speedup vs baseline: 1.0384x; 1.0292x over previous
//
#include <hip/hip_runtime.h>
#include <hip/hip_bf16.h>

// LSTM2: B=1024, T=1024, H=64. R20: R19 (decoupled P/Q flag pipelines) with
// the tail race fixed + cheaper poll. R19 failed absmax 2.39e-2: w4 read
// headl[(Tt-1)&1] for out(:,1023) right after its own loop exit, racing
// w5/6/7's step-1023 headl writes (group spread <=1 step; in-loop reads are
// covered by min(qf)>=u but the tail read had no guard). Fix: w4 polls
// min(qf)>=Tt before the tail read (all Q waves publish Tt unconditionally
// -> no deadlock). Poll rewritten lane-parallel: lane i reads flg[i&7]
// (8 banks, broadcast -> 1 conflict-free ds_read_b32), per-lane threshold,
// __all ballot (~20cy/spin, no s_sleep) vs 8 serial volatile reads + sleep.
// Protocol (audited R19/R20):
//  - h1 in 4-deep ring h1ring[t&3]; P up to 3 steps ahead of Q.
//  - flags flg[0..3]=pf (P waves), flg[4..7]=qf (Q waves); lane-0 publish
//    after data writes; same-wave DS ops complete in order -> no waitcnt.
//  - P(t): wait min(pf)>=t && min(qf)>=t-3.  Q(u): wait min(pf)>=u+1 &&
//    min(qf)>=u.  Publish-at-end bounds intra-group spread to 1 step ->
//    depth-2 h2buf/headl parity safe; ring-4 covers P's 3-step lead.
// R18 retained: masked h-frag reads (m<NBat), pre-scaled activations,
// DPP head reduce (sum at uo==15), setprio around MFMA, LDS outbuf,
// XOR swizzle scr.
// Layouts (m89/m91/m120): A[m=lane&15][k=(lane>>4)*8+j],
// B[k=(lane>>4)*8+j][n=lane&15], C/D: row=(lane>>4)*4+reg, col=lane&15.

typedef _Float16 f16x8 __attribute__((ext_vector_type(8)));
typedef float    f32x4 __attribute__((ext_vector_type(4)));

namespace {
constexpr int Bb = 1024;
constexpr int Tt = 1024;
constexpr int NBat = 4;    // batches per block
constexpr int HSTR = 72;   // f16 stride per batch row of h
constexpr int XSTR = 1025; // f32 stride per batch row of x

__device__ __forceinline__ int srow(int row) {      // XOR bank swizzle (R11)
    return row ^ ((row >> 3) & 7);
}
// Pre-scaled activations: gate rows of W/b folded with -log2e (i,f,o) and
// -2log2e (g) at load, so no input multiply here.
__device__ __forceinline__ float sigm_pre(float a) {   // a = -1.4427*x
    return __builtin_amdgcn_rcpf(1.0f + __builtin_amdgcn_exp2f(a));
}
__device__ __forceinline__ float tanh_pre(float a) {   // a = -2.8854*x
    return fmaf(2.0f, __builtin_amdgcn_rcpf(1.0f + __builtin_amdgcn_exp2f(a)), -1.0f);
}
__device__ __forceinline__ float tanh_f(float x) {     // unscaled input (c-path)
    float e = __builtin_amdgcn_exp2f(-2.8853900817779268f * x);
    return fmaf(2.0f, __builtin_amdgcn_rcpf(1.0f + e), -1.0f);
}
// DPP partial-sum: lane i += lane (i-N) in its 16-lane row (OOB->0).
// Sum accumulates toward lane 15.
template <int CTRL>
__device__ __forceinline__ float dpp_sum_step(float p) {
    int v = __builtin_amdgcn_update_dpp(0, __float_as_int(p), CTRL, 0xf, 0xf, true);
    return p + __int_as_float(v);
}
// Dtype sniff (proven R2-R18).
__device__ __forceinline__ bool detect_f32(const void* w) {
    const unsigned short* p = (const unsigned short*)w;
    int sane = 0;
    for (int i = 0; i < 64; ++i) {
        int e = (p[2 * i] >> 7) & 0xFF;
        if (e >= 107 && e <= 129) ++sane;
    }
    return sane < 32;
}
__device__ __forceinline__ float ld(const void* p, int i, bool f32) {
    return f32 ? ((const float*)p)[i]
               : __bfloat162float(((const __hip_bfloat16*)p)[i]);
}
__device__ __forceinline__ void st(void* p, int i, float v, bool f32) {
    if (f32) ((float*)p)[i] = v;
    else     ((__hip_bfloat16*)p)[i] = __float2bfloat16(v);
}
// Lane-parallel spin: lane i watches flg[i&7]; P-flags (idx<4) against tp,
// Q-flags against tq. One broadcast ds_read_b32 per spin, __all ballot.
__device__ __forceinline__ void poll_flags(const int* f, int tp, int tq, int lane) {
    const int idx = lane & 7;
    const int thr = (idx < 4) ? tp : tq;
    for (;;) {
        int v = ((const volatile int*)f)[idx];
        if (__all(v >= thr)) break;
    }
    __builtin_amdgcn_sched_barrier(0);
    asm volatile("" ::: "memory");
}
} // namespace

__global__ __launch_bounds__(512, 1) void lstm2_kernel(
    const void* __restrict__ x,      // [B, T]
    const void* __restrict__ w_ih1,  // [256, 1]
    const void* __restrict__ w_hh1,  // [256, 64]
    const void* __restrict__ b_ih1,  // [256]
    const void* __restrict__ b_hh1,  // [256]
    const void* __restrict__ w_ih2,  // [256, 64]
    const void* __restrict__ w_hh2,  // [256, 64]
    const void* __restrict__ b_ih2,  // [256]
    const void* __restrict__ b_hh2,  // [256]
    const void* __restrict__ w_lin,  // [1, 64]
    const void* __restrict__ b_lin,  // [1]
    void* __restrict__ out)          // [B, T]
{
    const int tid  = threadIdx.x;
    const int lane = tid & 63;
    const int w    = tid >> 6;       // wave 0..7
    const int gw   = w & 3;          // group-local wave -> unit group 16gw..
    const bool isP = w < 4;          // P: L1 recurrence; Q: L2 pipeline
    const int m    = lane & 15;      // MFMA col (batch; valid m<NBat)
    const int quad = lane >> 4;
    const int bb   = blockIdx.x * NBat;

    const bool f32 = detect_f32(w_hh1);

    __shared__ float                  xs[NBat * XSTR];
    __shared__ __align__(16) _Float16 h1ring[4][16 * HSTR]; // 4-deep ring
    __shared__ __align__(16) _Float16 h2buf[2][16 * HSTR];  // parity (Q-only)
    __shared__ __align__(16) float    scr1[4][64 * 4];      // P-wave scratch
    __shared__ __align__(16) float    scr2[4][64 * 4];      // Q-wave scratch
    __shared__ float                  headl[2][16];         // [parity][gw*4+b]
    __shared__ float                  outbuf[NBat * Tt];    // staged outputs
    __shared__ int                    flg[8];               // 0..3 pf, 4..7 qf

    // ---- stage x + zero h buffers (rows >= NBat stay 0 forever) ----
    for (int i = tid; i < NBat * 1024; i += 512)
        xs[(i >> 10) * XSTR + (i & 1023)] = ld(x, (bb + (i >> 10)) * Tt + (i & 1023), f32);
    for (int i = tid; i < 16 * HSTR; i += 512) {
        h1ring[0][i] = (_Float16)0; h1ring[1][i] = (_Float16)0;
        h1ring[2][i] = (_Float16)0; h1ring[3][i] = (_Float16)0;
        h2buf[0][i] = (_Float16)0;  h2buf[1][i] = (_Float16)0;
    }
    if (tid < 8) flg[tid] = 0;

    // ---- A-fragments, gate-interleaved rows (R13), activation-scale folded ----
    // tile row (lane&15) = 4*u_loc + g -> mem row 64*g + 16*gw + 4q + u_loc
    const int arow = lane & 15;
    const int g_ld = arow & 3;
    const int u_ld = arow >> 2;
    const float scA = (g_ld == 2) ? -2.8853900817779268f : -1.4426950408889634f;
    f16x8 wfA[4][2], wfB[4][2];   // P: wfA=W1 (wfB zero); Q: wfA=W2, wfB=W3
    {
        const void* MA = isP ? w_hh1 : w_ih2;
#pragma unroll
        for (int q = 0; q < 4; ++q) {
            const int row = 64 * g_ld + 16 * gw + 4 * q + u_ld;
#pragma unroll
            for (int s = 0; s < 2; ++s) {
                const int base = row * 64 + 32 * s + quad * 8;
                if (f32) {
                    const float* A = (const float*)MA;
                    const float* B = (const float*)w_hh2;
#pragma unroll
                    for (int j = 0; j < 8; ++j) {
                        wfA[q][s][j] = (_Float16)(scA * A[base + j]);
                        wfB[q][s][j] = isP ? (_Float16)0.0f
                                           : (_Float16)(scA * B[base + j]);
                    }
                } else {
                    const __hip_bfloat16* A = (const __hip_bfloat16*)MA;
                    const __hip_bfloat16* B = (const __hip_bfloat16*)w_hh2;
#pragma unroll
                    for (int j = 0; j < 8; ++j) {
                        wfA[q][s][j] = (_Float16)(scA * __bfloat162float(A[base + j]));
                        wfB[q][s][j] = isP ? (_Float16)0.0f
                                           : (_Float16)(scA * __bfloat162float(B[base + j]));
                    }
                }
            }
        }
    }
    // bias / wx per (tile q, gate r): D row r of tile q = gate r, unit 16gw+4q+quad
    f32x4 bv[4], wxv[4];
#pragma unroll
    for (int q = 0; q < 4; ++q)
#pragma unroll
        for (int r = 0; r < 4; ++r) {
            const int row = 64 * r + 16 * gw + 4 * q + quad;
            const float sg = (r == 2) ? -2.8853900817779268f : -1.4426950408889634f;
            bv[q][r] = sg * (isP ? (ld(b_ih1, row, f32) + ld(b_hh1, row, f32))
                                 : (ld(b_ih2, row, f32) + ld(b_hh2, row, f32)));
            wxv[q][r] = isP ? sg * ld(w_ih1, row, f32) : 0.0f;
        }
    // cell mapping: lane -> (batch cb, unit 16gw+uo)
    const int cb = lane >> 4;
    const int uo = lane & 15;
    const int cidx = srow(lane) * 4;
    int swadr[4];
#pragma unroll
    for (int q = 0; q < 4; ++q) swadr[q] = srow(m * 16 + q * 4 + quad) * 4;
    const float wl_u = ld(w_lin, 16 * gw + uo, f32);
    const float blin = ld(b_lin, 0, f32);
    float cst = 0.0f;                 // c1 (P) or c2 (Q)
    __syncthreads();   // xs + zeroed bufs + flags visible

    if (isP) {
        // ================= P: L1 recurrence, self-paced =================
        f16x8 pa0{}, pa1{};
#pragma unroll 4
        for (int t = 0; t < Tt; ++t) {
            poll_flags(flg, t, t - 3, lane);   // group sync + ring-not-full
            f32x4 acc[4];
            const float xt = xs[(m & (NBat - 1)) * XSTR + t];
#pragma unroll
            for (int q = 0; q < 4; ++q)
#pragma unroll
                for (int r = 0; r < 4; ++r)
                    acc[q][r] = fmaf(xt, wxv[q][r], bv[q][r]);
            if (t > 0) {
                const _Float16* hp = h1ring[(t - 1) & 3] + m * HSTR;
                if (m < NBat) {       // masked read: only valid batches
                    pa0 = *(const f16x8*)(hp + quad * 8);
                    pa1 = *(const f16x8*)(hp + 32 + quad * 8);
                }
                __builtin_amdgcn_s_setprio(1);
#pragma unroll
                for (int q = 0; q < 4; ++q) {
                    acc[q] = __builtin_amdgcn_mfma_f32_16x16x32_f16(wfA[q][0], pa0, acc[q], 0, 0, 0);
                    acc[q] = __builtin_amdgcn_mfma_f32_16x16x32_f16(wfA[q][1], pa1, acc[q], 0, 0, 0);
                }
                __builtin_amdgcn_s_setprio(0);
            }
            if (m < NBat)
#pragma unroll
                for (int q = 0; q < 4; ++q)
                    *(f32x4*)&scr1[gw][swadr[q]] = acc[q];
            const f32x4 g = *(const f32x4*)&scr1[gw][cidx];   // i,f,g,o
            float ig = sigm_pre(g[0]), fg = sigm_pre(g[1]);
            float gg = tanh_pre(g[2]), og = sigm_pre(g[3]);
            cst = fmaf(fg, cst, ig * gg);
            h1ring[t & 3][cb * HSTR + 16 * gw + uo] = (_Float16)(og * tanh_f(cst));
            if (lane == 0) {          // publish: DS in-order, no waitcnt
                asm volatile("" ::: "memory");
                *(volatile int*)&flg[gw] = t + 1;
            }
        }
    } else {
        // ================= Q: L2 pipeline, self-paced =================
        f16x8 pa0{}, pa1{}, pb0{}, pb1{};
#pragma unroll 4
        for (int u = 0; u < Tt; ++u) {
            poll_flags(flg, u + 1, u, lane);   // h1(u) ready + own group done u-1
            // ---- finalize out(u-1) -> LDS outbuf ----
            if (u > 0 && w == 4 && lane < NBat) {
                float s = blin;
#pragma unroll
                for (int k = 0; k < 4; ++k) s += headl[(u - 1) & 1][k * 4 + lane];
                outbuf[lane * Tt + (u - 1)] = s;
            }
            // ---- a2(u) = W2.h1(u) + W3.h2(u-1) + b2 (pre-scaled) ----
            const _Float16* h1p = h1ring[u & 3] + m * HSTR;
            const _Float16* h2p = h2buf[(u + 1) & 1] + m * HSTR;  // (u-1) parity
            if (m < NBat) {
                pa0 = *(const f16x8*)(h1p + quad * 8);
                pa1 = *(const f16x8*)(h1p + 32 + quad * 8);
                pb0 = *(const f16x8*)(h2p + quad * 8);
                pb1 = *(const f16x8*)(h2p + 32 + quad * 8);
            }
            f32x4 acc[4];
            __builtin_amdgcn_s_setprio(1);
#pragma unroll
            for (int q = 0; q < 4; ++q) {   // two independent 2-deep chains
                f32x4 p2 = __builtin_amdgcn_mfma_f32_16x16x32_f16(wfA[q][0], pa0, bv[q], 0, 0, 0);
                p2 = __builtin_amdgcn_mfma_f32_16x16x32_f16(wfA[q][1], pa1, p2, 0, 0, 0);
                f32x4 p3 = __builtin_amdgcn_mfma_f32_16x16x32_f16(wfB[q][0], pb0, f32x4{0,0,0,0}, 0, 0, 0);
                p3 = __builtin_amdgcn_mfma_f32_16x16x32_f16(wfB[q][1], pb1, p3, 0, 0, 0);
                acc[q] = p2 + p3;
            }
            __builtin_amdgcn_s_setprio(0);
            if (m < NBat)
#pragma unroll
                for (int q = 0; q < 4; ++q)
                    *(f32x4*)&scr2[gw][swadr[q]] = acc[q];
            // ---- cell2(u) + head partial ----
            const f32x4 g = *(const f32x4*)&scr2[gw][cidx];
            float ig = sigm_pre(g[0]), fg = sigm_pre(g[1]);
            float gg = tanh_pre(g[2]), og = sigm_pre(g[3]);
            cst = fmaf(fg, cst, ig * gg);
            float h = og * tanh_f(cst);
            h2buf[u & 1][cb * HSTR + 16 * gw + uo] = (_Float16)h;
            float p = h * wl_u;               // reduce over uo (same cb)
            p = dpp_sum_step<0x111>(p);       // row_shr:1
            p = dpp_sum_step<0x112>(p);       // row_shr:2
            p = dpp_sum_step<0x114>(p);       // row_shr:4
            p = dpp_sum_step<0x118>(p);       // row_shr:8
            if (uo == 15) headl[u & 1][gw * 4 + cb] = p;  // sum at lane 15
            if (lane == 0) {          // publish after h2+headl writes
                asm volatile("" ::: "memory");
                *(volatile int*)&flg[4 + gw] = u + 1;
            }
        }
        // ---- tail: out(Tt-1); MUST wait for all Q waves' step-(Tt-1) headl
        // writes (R19 bug: unguarded read raced w5/6/7 -> absmax 2.4e-2) ----
        if (w == 4) {
            poll_flags(flg, 0, Tt, lane);     // all Q published Tt
            if (lane < NBat) {
                float s = blin;
#pragma unroll
                for (int k = 0; k < 4; ++k) s += headl[(Tt - 1) & 1][k * 4 + lane];
                outbuf[lane * Tt + (Tt - 1)] = s;
            }
        }
    }
    __syncthreads();
    // ---- cooperative coalesced flush: LDS outbuf -> global out ----
    for (int i = tid; i < NBat * Tt; i += 512)
        st(out, (bb + (i >> 10)) * Tt + (i & 1023), outbuf[i], f32);
}

extern "C" void kernel_launch(void* const* d_in, const int* in_sizes, int n_in,
                              void* d_out, int out_size, void* d_ws, size_t ws_size,
                              hipStream_t stream)
{
    (void)in_sizes; (void)n_in; (void)out_size; (void)d_ws; (void)ws_size;
    lstm2_kernel<<<dim3(Bb / NBat), dim3(512), 0, stream>>>(
        d_in[0], d_in[1], d_in[2], d_in[3], d_in[4], d_in[5],
        d_in[6], d_in[7], d_in[8], d_in[9], d_in[10], d_out);
}